// Round 7
// baseline (1232.018 us; speedup 1.0000x reference)
//
#include <hip/hip_runtime.h>
#include <math.h>

#define BB 512
#define TT 1024
#define LL 48
#define PF 4            // emission prefetch depth (loads in flight, per wave)
#define WPB 16          // waves (=chains) per block -> 4 waves per SIMD
#define TSTRIDE 49      // padded T row stride: bank = (17*i + j) % 32, conflict-free

__device__ __forceinline__ float readlane_f(float v, int lane) {
    return __int_as_float(__builtin_amdgcn_readlane(__float_as_int(v), lane));
}

// One DPP butterfly/broadcast stage of a full-wave max (register-file cross-lane).
template <int CTRL>
__device__ __forceinline__ float dppmax(float x) {
    int y = __builtin_amdgcn_update_dpp(__float_as_int(x), __float_as_int(x),
                                        CTRL, 0xF, 0xF, false);
    return fmaxf(x, __int_as_float(y));
}

// Wave max of z, then lowest-lane index of bitwise equality (== reference
// first-max argmax; lanes holding -INF never match). ~13 VALU + 1 SALU.
__device__ __forceinline__ int wave_argmax(float z) {
    float r = z;
    r = dppmax<0xB1>(r);    // quad_perm [1,0,3,2] : xor 1
    r = dppmax<0x4E>(r);    // quad_perm [2,3,0,1] : xor 2
    r = dppmax<0x141>(r);   // row_half_mirror     : xor 4
    r = dppmax<0x140>(r);   // row_mirror          : xor 8
    r = dppmax<0x142>(r);   // row_bcast15         : 16->31, 47->63 merge
    r = dppmax<0x143>(r);   // row_bcast31         : lane 63 = full-wave max
    float m = readlane_f(r, 63);
    unsigned long long eq = __ballot(z == m);
    return (int)__builtin_ctzll(eq);     // s_ff1: lowest index wins ties
}

// Forward stores VALUES ONLY; backtrack recomputes the one on-path argmax per
// step (bitwise-identical floats, ffs tie-break).
//
// TLP packing: 16 waves/block -> 4 waves per SIMD, one chain per wave, no
// inter-wave communication (no barriers; tlds written redundantly with
// identical values). Rounds 0-6 showed a ~560-660 cyc/step latency stall
// invariant to the step body's content; with 1 wave/SIMD nothing fills it.
// 4 co-resident waves let the hardware interleave 4 chains -> issue-bound.
// 1024-thread blocks force VGPR <= 128 (512/4); PF=4 shaves the ring to fit.
__global__ __launch_bounds__(WPB * 64) void viterbi_kernel(
    const float* __restrict__ emissions,   // [B,T,L]
    const float* __restrict__ transitions, // [L,L]
    const float* __restrict__ start_tr,    // [L]
    const float* __restrict__ end_tr,      // [L]
    int* __restrict__ out,                 // [B,T] int32
    float* __restrict__ vws)               // workspace: [B][T][L] viterbi rows
{
    __shared__ float tlds[LL * TSTRIDE];   // T padded for backtrack column reads

    const int wid = threadIdx.x >> 6;             // wave id within block
    const int b   = blockIdx.x * WPB + wid;       // one chain per wave
    const int j   = threadIdx.x & 63;
    const int jc  = (j < LL) ? j : (LL - 1);      // lanes 48-63 mirror lane 47

    // Transition column jc in registers (forward); T into LDS (backtrack).
    // All waves write identical values to tlds -> benign redundancy, no sync.
    float tc[LL];
#pragma unroll
    for (int i = 0; i < LL; ++i) {
        tc[i] = transitions[i * LL + jc];
        tlds[i * TSTRIDE + jc] = tc[i];
    }
#pragma unroll
    for (int i = 0; i < LL; ++i)
        asm volatile("" : "+v"(tc[i]));    // pin: forbid remat-as-load (round-4 mode)

    const float* em = emissions + (size_t)b * TT * LL;
    float* vr_g = vws + (size_t)b * TT * LL;      // this chain's [T][48] rows

    float v = start_tr[jc] + em[jc];
    vr_g[jc] = v;                                  // row 0 (dup lanes: same value)

    // PF-deep emission prefetch ring.
    float er[PF];
#pragma unroll
    for (int k = 0; k < PF; ++k)
        er[k] = em[(size_t)(1 + k) * LL + jc];

    // One value-only Viterbi step (serial chain: v -> v).
    auto step = [&](int t, float e) {
        float s[LL];
#pragma unroll
        for (int i = 0; i < LL; ++i)
            s[i] = readlane_f(v, i) + tc[i];

        float m1[16];
#pragma unroll
        for (int k = 0; k < 16; ++k)
            m1[k] = fmaxf(fmaxf(s[3 * k], s[3 * k + 1]), s[3 * k + 2]);
        float m2[6];
#pragma unroll
        for (int k = 0; k < 5; ++k)
            m2[k] = fmaxf(fmaxf(m1[3 * k], m1[3 * k + 1]), m1[3 * k + 2]);
        m2[5] = m1[15];
        float best = fmaxf(fmaxf(fmaxf(m2[0], m2[1]), m2[2]),
                           fmaxf(fmaxf(m2[3], m2[4]), m2[5]));

        v = best + e;                              // chain continues here
        vr_g[(size_t)t * LL + jc] = v;             // off-chain coalesced store
    };

    // Main loop: blocks of PF with compile-time-constant ring indices.
    int tb = 1;
    for (; tb + PF <= TT; tb += PF) {
#pragma unroll
        for (int k = 0; k < PF; ++k) {
            int t = tb + k;
            float e = er[k];
            int tn = t + PF; if (tn > TT - 1) tn = TT - 1;   // scalar clamp
            er[k] = em[(size_t)tn * LL + jc];      // refill: PF loads in flight
            step(t, e);
        }
    }
#pragma unroll
    for (int k = 0; k < PF - 1; ++k) {
        int t = tb + k;
        if (t < TT) step(t, er[k]);
    }

    // ---- final tag: wave-parallel argmax of v + end ----
    float vf = (j < LL) ? (v + end_tr[jc]) : -INFINITY;
    int tag = wave_argmax(vf);                     // uniform (SGPR) tag

    int* ob = out + (size_t)b * TT;
    if (j == 0) ob[TT - 1] = tag;

    // ---- backtrack: recompute argmax only along the path ----
    // tag_p = argmax_i( v_p[i] + T[i][tag_{p+1}] ), p = T-2 .. 0.
    for (int hi = TT - 2; hi >= 0; hi -= 32) {
        int lo = hi - 31; if (lo < 0) lo = 0;
        int n = hi - lo + 1;                       // wave-uniform

        float vr[32];
#pragma unroll
        for (int k = 31; k >= 0; --k)              // issue order == consume order
            if (k < n) vr[k] = vr_g[(size_t)(lo + k) * LL + jc];

        int outv = 0;
#pragma unroll
        for (int k = 31; k >= 0; --k) {
            if (k < n) {
                // lane i reads T[i][tag]: dwords (17*i + tag) % 32 -> no conflicts
                float tcol = tlds[jc * TSTRIDE + tag];
                float z = (j < LL) ? (vr[k] + tcol) : -INFINITY;
                tag = wave_argmax(z);              // chain: ds_read+add+dpp+ballot
                outv = (j == k) ? tag : outv;      // tag is SGPR -> one cndmask
            }
        }
        if (j < n) ob[lo + j] = outv;
    }
}

extern "C" void kernel_launch(void* const* d_in, const int* in_sizes, int n_in,
                              void* d_out, int out_size, void* d_ws, size_t ws_size,
                              hipStream_t stream) {
    const float* emissions   = (const float*)d_in[0];
    // d_in[1] = mask — unused by the reference decode body
    const float* transitions = (const float*)d_in[2];
    const float* start_tr    = (const float*)d_in[3];
    const float* end_tr      = (const float*)d_in[4];
    int* out = (int*)d_out;

    // Viterbi rows: B * T * L * 4 = 100,663,296 B in the provided workspace.
    float* vws = (float*)d_ws;

    viterbi_kernel<<<dim3(BB / WPB), dim3(WPB * 64), 0, stream>>>(
        emissions, transitions, start_tr, end_tr, out, vws);
}

// Round 9
// 498.144 us; speedup vs baseline: 2.4732x; 2.4732x over previous
//
#include <hip/hip_runtime.h>
#include <math.h>

#define BB 512
#define TT 1024
#define LL 48
#define PF 8            // emission prefetch depth (loads in flight)
#define TSTRIDE 49      // padded T row stride: bank = (17*i + j) % 32, conflict-free

__device__ __forceinline__ float readlane_f(float v, int lane) {
    return __int_as_float(__builtin_amdgcn_readlane(__float_as_int(v), lane));
}

// One DPP butterfly/broadcast stage of a full-wave max (register-file cross-lane).
template <int CTRL>
__device__ __forceinline__ float dppmax(float x) {
    int y = __builtin_amdgcn_update_dpp(__float_as_int(x), __float_as_int(x),
                                        CTRL, 0xF, 0xF, false);
    return fmaxf(x, __int_as_float(y));
}

// Wave max of z, then lowest-lane index of bitwise equality (== reference
// first-max argmax; lanes holding -INF never match). ~13 VALU + 1 SALU.
__device__ __forceinline__ int wave_argmax(float z) {
    float r = z;
    r = dppmax<0xB1>(r);    // quad_perm [1,0,3,2] : xor 1
    r = dppmax<0x4E>(r);    // quad_perm [2,3,0,1] : xor 2
    r = dppmax<0x141>(r);   // row_half_mirror     : xor 4
    r = dppmax<0x140>(r);   // row_mirror          : xor 8
    r = dppmax<0x142>(r);   // row_bcast15         : 16->31, 47->63 merge
    r = dppmax<0x143>(r);   // row_bcast31         : lane 63 = full-wave max
    float m = readlane_f(r, 63);
    unsigned long long eq = __ballot(z == m);
    return (int)__builtin_ctzll(eq);     // s_ff1: lowest index wins ties
}

// Forward stores VALUES ONLY; backtrack recomputes the one on-path argmax per
// step (bitwise-identical floats, ffs tie-break).
//
// Broadcast via LDS same-address reads (round-9, aliasing-FIXED round 8):
// lane j writes v[j] to a per-wave LDS buffer (1 ds_write_b32, unmasked into
// a 64-slot buffer), all lanes read the 48 floats back as 12 ds_read_b128 at
// WAVE-UNIFORM addresses (same-address = hardware broadcast, conflict-free).
// Round-8 read through (float4*)cast -> TBAA said no alias with the float
// store -> reads hoisted above the write -> stale rows (absmax=47). Now the
// reads go through __builtin_memcpy (aliases vbuf in the compiler's model)
// plus a compile-time memory fence. Hardware DS pipe is in-order per wave,
// so write->read needs no explicit lgkmcnt; the compiler inserts the
// consume-side wait for q.
__global__ __launch_bounds__(64)
__attribute__((amdgpu_waves_per_eu(1, 1)))
void viterbi_kernel(
    const float* __restrict__ emissions,   // [B,T,L]
    const float* __restrict__ transitions, // [L,L]
    const float* __restrict__ start_tr,    // [L]
    const float* __restrict__ end_tr,      // [L]
    int* __restrict__ out,                 // [B,T] int32
    float* __restrict__ vws)               // workspace: [B][T][L] viterbi rows
{
    __shared__ float tlds[LL * TSTRIDE];   // T padded for backtrack column reads
    __shared__ __align__(16) float vbuf[64];      // v broadcast buffer (48 + slack)

    const int b  = blockIdx.x;
    const int j  = threadIdx.x;
    const int jc = (j < LL) ? j : (LL - 1);       // lanes 48-63 mirror lane 47

    // Transition column jc in registers (forward); T into LDS (backtrack).
    float tc[LL];
#pragma unroll
    for (int i = 0; i < LL; ++i) {
        tc[i] = transitions[i * LL + jc];
        tlds[i * TSTRIDE + jc] = tc[i];    // lanes 48-63 dup-write col 47: same value
    }
#pragma unroll
    for (int i = 0; i < LL; ++i)
        asm volatile("" : "+v"(tc[i]));    // pin: forbid remat-as-load (round-4 mode)

    const float* em = emissions + (size_t)b * TT * LL;
    float* vr_g = vws + (size_t)b * TT * LL;      // this chain's [T][48] rows

    float v = start_tr[jc] + em[jc];
    vr_g[jc] = v;                                  // row 0 (dup lanes: same value)

    // PF-deep emission prefetch ring.
    float er[PF];
#pragma unroll
    for (int k = 0; k < PF; ++k)
        er[k] = em[(size_t)(1 + k) * LL + jc];

    // One value-only Viterbi step (serial chain: v -> LDS -> v).
    auto step = [&](int t, float e) {
        vbuf[j] = v;                       // 1 ds_write_b32 (lanes 48-63: slack)
        asm volatile("" ::: "memory");     // compile-time order: write before reads

        float s[LL];
#pragma unroll
        for (int r = 0; r < 12; ++r) {
            float4 q;
            __builtin_memcpy(&q, &vbuf[4 * r], 16);   // ds_read_b128, uniform addr
            s[4 * r + 0] = q.x + tc[4 * r + 0];
            s[4 * r + 1] = q.y + tc[4 * r + 1];
            s[4 * r + 2] = q.z + tc[4 * r + 2];
            s[4 * r + 3] = q.w + tc[4 * r + 3];
        }

        float m1[16];
#pragma unroll
        for (int k = 0; k < 16; ++k)
            m1[k] = fmaxf(fmaxf(s[3 * k], s[3 * k + 1]), s[3 * k + 2]);
        float m2[6];
#pragma unroll
        for (int k = 0; k < 5; ++k)
            m2[k] = fmaxf(fmaxf(m1[3 * k], m1[3 * k + 1]), m1[3 * k + 2]);
        m2[5] = m1[15];
        float best = fmaxf(fmaxf(fmaxf(m2[0], m2[1]), m2[2]),
                           fmaxf(fmaxf(m2[3], m2[4]), m2[5]));

        v = best + e;                              // chain continues here
        vr_g[(size_t)t * LL + jc] = v;             // off-chain coalesced store
    };

    // Main loop: blocks of PF with compile-time-constant ring indices.
    int tb = 1;
    for (; tb + PF <= TT; tb += PF) {
#pragma unroll
        for (int k = 0; k < PF; ++k) {
            int t = tb + k;
            float e = er[k];
            int tn = t + PF; if (tn > TT - 1) tn = TT - 1;   // scalar clamp
            er[k] = em[(size_t)tn * LL + jc];      // refill: PF loads in flight
            step(t, e);
        }
    }
#pragma unroll
    for (int k = 0; k < PF - 1; ++k) {
        int t = tb + k;
        if (t < TT) step(t, er[k]);
    }

    // ---- final tag: wave-parallel argmax of v + end ----
    float vf = (j < LL) ? (v + end_tr[jc]) : -INFINITY;
    int tag = wave_argmax(vf);                     // uniform (SGPR) tag

    int* ob = out + (size_t)b * TT;
    if (j == 0) ob[TT - 1] = tag;

    // ---- backtrack: recompute argmax only along the path ----
    // tag_p = argmax_i( v_p[i] + T[i][tag_{p+1}] ), p = T-2 .. 0.
    for (int hi = TT - 2; hi >= 0; hi -= 32) {
        int lo = hi - 31; if (lo < 0) lo = 0;
        int n = hi - lo + 1;                       // wave-uniform

        float vr[32];
#pragma unroll
        for (int k = 31; k >= 0; --k)              // issue order == consume order
            if (k < n) vr[k] = vr_g[(size_t)(lo + k) * LL + jc];

        int outv = 0;
#pragma unroll
        for (int k = 31; k >= 0; --k) {
            if (k < n) {
                // lane i reads T[i][tag]: dwords (17*i + tag) % 32 -> no conflicts
                float tcol = tlds[jc * TSTRIDE + tag];
                float z = (j < LL) ? (vr[k] + tcol) : -INFINITY;
                tag = wave_argmax(z);              // chain: ds_read+add+dpp+ballot
                outv = (j == k) ? tag : outv;      // tag is SGPR -> one cndmask
            }
        }
        if (j < n) ob[lo + j] = outv;
    }
}

extern "C" void kernel_launch(void* const* d_in, const int* in_sizes, int n_in,
                              void* d_out, int out_size, void* d_ws, size_t ws_size,
                              hipStream_t stream) {
    const float* emissions   = (const float*)d_in[0];
    // d_in[1] = mask — unused by the reference decode body
    const float* transitions = (const float*)d_in[2];
    const float* start_tr    = (const float*)d_in[3];
    const float* end_tr     = (const float*)d_in[4];
    int* out = (int*)d_out;

    // Viterbi rows: B * T * L * 4 = 100,663,296 B in the provided workspace.
    float* vws = (float*)d_ws;

    viterbi_kernel<<<dim3(BB), dim3(64), 0, stream>>>(
        emissions, transitions, start_tr, end_tr, out, vws);
}